// Round 2
// baseline (299.302 us; speedup 1.0000x reference)
//
#include <hip/hip_runtime.h>

#define T_DIM 16384
#define B_DIM 64
#define E_DIM 4096

typedef float f4 __attribute__((ext_vector_type(4)));

// ---------------------------------------------------------------------------
// K1: coeff[t] = sum over b of params[indices[t,b], :]  (alpha, beta as float2)
// One wave (64 lanes) per t; lane b gathers float2 params[idx]; shuffle-reduce.
// ---------------------------------------------------------------------------
__global__ __launch_bounds__(256) void coeff_kernel(const int* __restrict__ indices,
                                                    const float* __restrict__ params,
                                                    float2* __restrict__ coeff) {
    int gid = blockIdx.x * blockDim.x + threadIdx.x;   // gid = t*64 + b
    int t = gid >> 6;
    int lane = threadIdx.x & 63;
    int idx = indices[gid];
    float2 p = ((const float2*)params)[idx];
    float a = p.x, b = p.y;
    #pragma unroll
    for (int off = 32; off >= 1; off >>= 1) {
        a += __shfl_down(a, off, 64);
        b += __shfl_down(b, off, 64);
    }
    if (lane == 0) coeff[t] = make_float2(a, b);
}

// ---------------------------------------------------------------------------
// K2: inclusive affine-recurrence scan over T elements, single block.
// compose(earlier (a1,b1), later (a2,b2)) = (a2*a1, a2*b1 + b2); identity (1,0).
// 1024 threads x 16 elements: serial local scan -> wave shuffle scan (no
// barriers) -> 16-wave-aggregate scan -> apply prefix. Only 2 barriers.
// ---------------------------------------------------------------------------
__global__ __launch_bounds__(1024) void scan_kernel(const float2* __restrict__ coeff,
                                                    float2* __restrict__ AB) {
    __shared__ float2 wagg[16];
    const int tid  = threadIdx.x;
    const int lane = tid & 63;
    const int w    = tid >> 6;
    const int base = tid * 16;

    // serial scan of 16 elements (loaded as 8 float4 = 16 float2 coeffs)
    float la[16], lb[16];
    float a = 1.0f, b = 0.0f;
    const f4* __restrict__ c4 = (const f4*)(coeff + base);
    #pragma unroll
    for (int j4 = 0; j4 < 8; ++j4) {
        f4 c = c4[j4];
        a = c.x * a; b = c.x * b + c.y; la[2*j4]   = a; lb[2*j4]   = b;
        a = c.z * a; b = c.z * b + c.w; la[2*j4+1] = a; lb[2*j4+1] = b;
    }

    // wave-level inclusive scan of thread aggregates (no barriers)
    #pragma unroll
    for (int off = 1; off < 64; off <<= 1) {
        float pa = __shfl_up(a, off, 64);
        float pb = __shfl_up(b, off, 64);
        if (lane >= off) { b = a * pb + b; a = a * pa; }
    }
    if (lane == 63) wagg[w] = make_float2(a, b);
    __syncthreads();

    // scan the 16 wave aggregates with wave 0, lanes 0..15
    if (w == 0 && lane < 16) {
        float wa = wagg[lane].x, wb = wagg[lane].y;
        #pragma unroll
        for (int off = 1; off < 16; off <<= 1) {
            float pa = __shfl_up(wa, off, 64);
            float pb = __shfl_up(wb, off, 64);
            if (lane >= off) { wb = wa * pb + wb; wa = wa * pa; }
        }
        wagg[lane] = make_float2(wa, wb);
    }
    __syncthreads();

    // thread's global exclusive prefix = compose(wave prefix, within-wave excl)
    float ea = __shfl_up(a, 1, 64);
    float eb = __shfl_up(b, 1, 64);
    if (lane == 0) { ea = 1.0f; eb = 0.0f; }
    float wa = 1.0f, wb = 0.0f;
    if (w > 0) { wa = wagg[w - 1].x; wb = wagg[w - 1].y; }
    float Pa = ea * wa;
    float Pb = ea * wb + eb;

    // apply prefix and store A,B interleaved as float2 (8 float4 stores)
    f4* __restrict__ o4 = (f4*)(AB + base);
    #pragma unroll
    for (int j4 = 0; j4 < 8; ++j4) {
        f4 r;
        r.x = la[2*j4]   * Pa;  r.y = la[2*j4]   * Pb + lb[2*j4];
        r.z = la[2*j4+1] * Pa;  r.w = la[2*j4+1] * Pb + lb[2*j4+1];
        o4[j4] = r;
    }
}

// ---------------------------------------------------------------------------
// K3: out[t, e] = A[t] * M_prev[e] + B[t]   (write-BW bound)
// 8 rows per block; M_prev held in 4 float4 registers; nontemporal stores.
// ---------------------------------------------------------------------------
#define ROWS_PER_BLOCK 8
__global__ __launch_bounds__(256) void out_kernel(const float2* __restrict__ AB,
                                                  const float* __restrict__ M,
                                                  float* __restrict__ out) {
    const int t0  = blockIdx.x * ROWS_PER_BLOCK;
    const int tid = threadIdx.x;
    const f4* __restrict__ M4 = (const f4*)M;
    f4 m0 = M4[tid];
    f4 m1 = M4[tid + 256];
    f4 m2 = M4[tid + 512];
    f4 m3 = M4[tid + 768];
    #pragma unroll
    for (int r = 0; r < ROWS_PER_BLOCK; ++r) {
        const int t = t0 + r;
        float2 ab = AB[t];
        const float a = ab.x, b = ab.y;
        f4* __restrict__ O4 = (f4*)(out + (size_t)t * E_DIM);
        f4 v0 = { a * m0.x + b, a * m0.y + b, a * m0.z + b, a * m0.w + b };
        f4 v1 = { a * m1.x + b, a * m1.y + b, a * m1.z + b, a * m1.w + b };
        f4 v2 = { a * m2.x + b, a * m2.y + b, a * m2.z + b, a * m2.w + b };
        f4 v3 = { a * m3.x + b, a * m3.y + b, a * m3.z + b, a * m3.w + b };
        __builtin_nontemporal_store(v0, O4 + tid);
        __builtin_nontemporal_store(v1, O4 + tid + 256);
        __builtin_nontemporal_store(v2, O4 + tid + 512);
        __builtin_nontemporal_store(v3, O4 + tid + 768);
    }
}

extern "C" void kernel_launch(void* const* d_in, const int* in_sizes, int n_in,
                              void* d_out, int out_size, void* d_ws, size_t ws_size,
                              hipStream_t stream) {
    const int*   indices = (const int*)d_in[0];     // (T, B) int32
    const float* M_prev  = (const float*)d_in[1];   // (E,)
    const float* params  = (const float*)d_in[2];   // (N, 2)
    float* out = (float*)d_out;

    float2* coeff = (float2*)d_ws;                  // T float2
    float2* AB    = ((float2*)d_ws) + T_DIM;        // T float2

    coeff_kernel<<<(T_DIM * B_DIM) / 256, 256, 0, stream>>>(indices, params, coeff);
    scan_kernel<<<1, 1024, 0, stream>>>(coeff, AB);
    out_kernel<<<T_DIM / ROWS_PER_BLOCK, 256, 0, stream>>>(AB, M_prev, out);
}